// Round 9
// baseline (4949.311 us; speedup 1.0000x reference)
//
#include <hip/hip_runtime.h>
#include <stdint.h>

// Problem constants
#define B_ 32
#define T_ 2048
#define D_ 512
#define N_ 512
#define NG 2048   // 4 gates * N

typedef _Float16 f16;
typedef _Float16 half2v __attribute__((ext_vector_type(2)));
typedef _Float16 half8  __attribute__((ext_vector_type(8)));
typedef float    float4v __attribute__((ext_vector_type(4)));
typedef unsigned long long u64;

union U32H2 { unsigned u; half2v h; };
union U4H8  { uint4 u; half8 h; };
union H16U  { f16 h; unsigned short s; };

static __device__ __forceinline__ float fast_sigmoid(float x) {
    return __builtin_amdgcn_rcpf(1.f + __expf(-x));
}
static __device__ __forceinline__ float fast_tanh(float x) {
    // 1 - 2/(1+e^{2x}): correct limits at +/-inf, no clamp needed
    return 1.f - 2.f * __builtin_amdgcn_rcpf(1.f + __expf(2.f * x));
}

// ---------------- prep: cast x (f32) -> f16 ----------------
__global__ void prep_cast(const float* __restrict__ x, f16* __restrict__ x16) {
    long i = ((long)blockIdx.x * 256 + threadIdx.x) * 4;
    float4 v = *(const float4*)(x + i);
    union { f16 h[4]; uint2 u; } pk;
    pk.h[0] = (f16)v.x; pk.h[1] = (f16)v.y; pk.h[2] = (f16)v.z; pk.h[3] = (f16)v.w;
    *(uint2*)(x16 + i) = pk.u;
}

// ---------------- prep: transpose+cast weights, biases ----------------
__global__ void prep_w(const float* __restrict__ Wi, const float* __restrict__ Ui,
                       const float* __restrict__ Wf, const float* __restrict__ Uf,
                       const float* __restrict__ Wg, const float* __restrict__ Ug,
                       const float* __restrict__ Wc, const float* __restrict__ Uc,
                       const float* __restrict__ Wo,
                       const float* __restrict__ bi, const float* __restrict__ bff,
                       const float* __restrict__ bg, const float* __restrict__ bc,
                       f16* __restrict__ wt, f16* __restrict__ ut,
                       f16* __restrict__ wot, float* __restrict__ bias)
{
    const int y = blockIdx.y;
    const int e = blockIdx.x * 256 + threadIdx.x;   // 0..262143
    if (y < 4) {
        const float* src = (y == 0) ? Wi : (y == 1) ? Wf : (y == 2) ? Wg : Wc;
        int col = e >> 9, d = e & 511;
        wt[(long)y * 512 * 512 + e] = (f16)src[(long)d * 512 + col];   // wt[(g*512+col)][d]
    } else if (y < 8) {
        const float* src = (y == 4) ? Ui : (y == 5) ? Uf : (y == 6) ? Ug : Uc;
        int col = e >> 9, d = e & 511;
        ut[(long)(y - 4) * 512 * 512 + e] = (f16)src[(long)d * 512 + col];
    } else if (y == 8) {
        int col = e >> 9, d = e & 511;
        wot[e] = (f16)Wo[(long)d * 512 + col];
    } else {
        if (e < 2048) {
            const float* bsrc = (e < 512) ? bi : (e < 1024) ? bff : (e < 1536) ? bg : bc;
            bias[e] = bsrc[e & 511];
        }
    }
}

// ---------------- phase 1: xpre[b][t][2048] = x @ [Wi|Wf|Wg|Wc] + bias (f16 out) ----------------
__launch_bounds__(256)
__global__ void gemm_xw(const f16* __restrict__ A, const f16* __restrict__ Bt,
                        const float* __restrict__ bias, f16* __restrict__ C)
{
    __shared__ f16 sA[128 * 32];
    __shared__ f16 sB[128 * 32];
    const int tid = threadIdx.x;
    const int m0 = blockIdx.y * 128;
    const int n0 = blockIdx.x * 128;
    const int wave = tid >> 6, lane = tid & 63;
    const int wm = wave >> 1, wn = wave & 1;
    const int lrow = lane & 15, quad = lane >> 4;

    float4v acc[4][4];
#pragma unroll
    for (int i = 0; i < 4; i++)
#pragma unroll
        for (int j = 0; j < 4; j++) acc[i][j] = (float4v){0.f, 0.f, 0.f, 0.f};

    const int srow = tid >> 2;        // 0..63
    const int sk8 = (tid & 3) * 8;    // 0,8,16,24

    for (int k0 = 0; k0 < 512; k0 += 32) {
#pragma unroll
        for (int rr = 0; rr < 128; rr += 64) {
            const int row = rr + srow;
            *(uint4*)&sA[row * 32 + sk8] = *(const uint4*)&A[(long)(m0 + row) * 512 + k0 + sk8];
            *(uint4*)&sB[row * 32 + sk8] = *(const uint4*)&Bt[(long)(n0 + row) * 512 + k0 + sk8];
        }
        __syncthreads();
        half8 af[4], bf[4];
#pragma unroll
        for (int mi = 0; mi < 4; mi++)
            af[mi] = *(half8*)&sA[(wm * 64 + mi * 16 + lrow) * 32 + quad * 8];
#pragma unroll
        for (int ni = 0; ni < 4; ni++)
            bf[ni] = *(half8*)&sB[(wn * 64 + ni * 16 + lrow) * 32 + quad * 8];
#pragma unroll
        for (int mi = 0; mi < 4; mi++)
#pragma unroll
            for (int ni = 0; ni < 4; ni++)
                acc[mi][ni] = __builtin_amdgcn_mfma_f32_16x16x32_f16(af[mi], bf[ni], acc[mi][ni], 0, 0, 0);
        __syncthreads();
    }
#pragma unroll
    for (int mi = 0; mi < 4; mi++)
#pragma unroll
        for (int ni = 0; ni < 4; ni++)
#pragma unroll
            for (int r = 0; r < 4; r++) {
                int m = m0 + wm * 64 + mi * 16 + quad * 4 + r;
                int n = n0 + wn * 64 + ni * 16 + lrow;
                C[(long)m * NG + n] = (f16)(acc[mi][ni][r] + bias[n]);
            }
}

// ---------------- phase 3: out[b][t][n] = relu(hs @ Wo + bo) (f32 out, row remap) ----------------
__launch_bounds__(256)
__global__ void gemm_hw(const f16* __restrict__ A, const f16* __restrict__ Bt,
                        const float* __restrict__ bias, float* __restrict__ out)
{
    __shared__ f16 sA[128 * 32];
    __shared__ f16 sB[128 * 32];
    const int tid = threadIdx.x;
    const int m0 = blockIdx.y * 128;
    const int n0 = blockIdx.x * 128;
    const int wave = tid >> 6, lane = tid & 63;
    const int wm = wave >> 1, wn = wave & 1;
    const int lrow = lane & 15, quad = lane >> 4;

    float4v acc[4][4];
#pragma unroll
    for (int i = 0; i < 4; i++)
#pragma unroll
        for (int j = 0; j < 4; j++) acc[i][j] = (float4v){0.f, 0.f, 0.f, 0.f};

    const int srow = tid >> 2;
    const int sk8 = (tid & 3) * 8;

    for (int k0 = 0; k0 < 512; k0 += 32) {
#pragma unroll
        for (int rr = 0; rr < 128; rr += 64) {
            const int row = rr + srow;
            *(uint4*)&sA[row * 32 + sk8] = *(const uint4*)&A[(long)(m0 + row) * 512 + k0 + sk8];
            *(uint4*)&sB[row * 32 + sk8] = *(const uint4*)&Bt[(long)(n0 + row) * 512 + k0 + sk8];
        }
        __syncthreads();
        half8 af[4], bf[4];
#pragma unroll
        for (int mi = 0; mi < 4; mi++)
            af[mi] = *(half8*)&sA[(wm * 64 + mi * 16 + lrow) * 32 + quad * 8];
#pragma unroll
        for (int ni = 0; ni < 4; ni++)
            bf[ni] = *(half8*)&sB[(wn * 64 + ni * 16 + lrow) * 32 + quad * 8];
#pragma unroll
        for (int mi = 0; mi < 4; mi++)
#pragma unroll
            for (int ni = 0; ni < 4; ni++)
                acc[mi][ni] = __builtin_amdgcn_mfma_f32_16x16x32_f16(af[mi], bf[ni], acc[mi][ni], 0, 0, 0);
        __syncthreads();
    }
#pragma unroll
    for (int mi = 0; mi < 4; mi++)
#pragma unroll
        for (int ni = 0; ni < 4; ni++)
#pragma unroll
            for (int r = 0; r < 4; r++) {
                int m = m0 + wm * 64 + mi * 16 + quad * 4 + r;   // m = t*B + b
                int n = n0 + wn * 64 + ni * 16 + lrow;
                float v = acc[mi][ni][r] + bias[n];
                v = fmaxf(v, 0.f);
                int t = m >> 5, b = m & 31;
                out[(long)b * (T_ * (long)N_) + (long)t * N_ + n] = v;
            }
}

// ---------------- phase 2: the recurrence (single-barrier, in-wave gates) ----------------
// Ring/handoff byte-identical to R7 (best measured): 32 batch-rings x 8 blocks
// x 512 threads; tid<256 polls ONE tagged slot, coalesced; parity double-
// buffered hg64; raw barriers. Changes vs R7 (structure only, inside the CU):
//  (1) Wave's 16 MFMA B-cols remapped to 4 GATES x 4 e-cols (2 col-tiles ->
//      wave owns all 4 gates of e-cols [8w,8w+8)). A-frags shared across both
//      tiles: still 16 conflict-free broadcast ds_read_b128 + 32 MFMA per wave
//      (R7's exact counts -- the phase is LDS-issue-bound, R8 proved halving
//      MFMAs alone buys nothing).
//  (2) After MFMA, the 4 gate pre-acts of a column live in 4 lanes of the SAME
//      wave -> gates via shfl_xor(4/8) butterfly, all 512 lanes parallel.
//      DELETED: prelds exchange, barrier2, serial tid<64 gate phase.
//  (3) hbuf parity-double-buffered (2x1KB) -> ONE barrier/step suffices.
//      In-block safety: a thread writing hbuf parity p at step t+2 passed
//      barrier1(t+1), so every wave completed its MFMA reads of parity p
//      (step t) before the overwrite. Cross-block slot-reuse safety unchanged:
//      producer passing poll(t) implies every peer block passed barrier1(t-1),
//      hence finished reading tag t-1 from the parity slots being overwritten.
//  (4) Poll spin is tight (no s_sleep): detect quantization was ~64cy/retry;
//      1-slot/thread coalesced spin traffic is ~500B/wave per L2 round trip.
__launch_bounds__(512, 2)
__global__ void lstm_rec(const f16* __restrict__ Ut,      // [2048 cols][512 rows] f16
                         const f16* __restrict__ xpre,    // [B][T][2048] f16
                         u64* __restrict__ hg64,          // [2][32][256] tagged h pairs
                         unsigned* __restrict__ hs32,     // [T][B][256] u32 (packed f16x2)
                         int unused)
{
    const int tid = threadIdx.x;
    const int bb = blockIdx.x & 31;   // batch (ring)
    const int s  = blockIdx.x >> 5;   // slice 0..7 (ring blocks 32 apart -> same XCD)
    const int w    = tid >> 6;        // wave 0..7: owns e-cols [8w, 8w+8) of slice
    const int lane = tid & 63;
    const int quad = lane >> 4;
    const int lcol = lane & 15;
    const int g  = lcol >> 2;         // gate of this lane's B-col
    const int eo = lcol & 3;          // e-offset within col-tile

    __shared__ __align__(16) unsigned hbuf[2][256];   // parity-double-buffered h_{t-1}

    // ---- persistent B-fragments: 2 col-tiles x 16 K-steps ----
    // B col n of tile tau = gate (n>>2), e-col s*64 + 8w + tau*4 + (n&3).
    half8 bfr[2][16];
#pragma unroll
    for (int tau = 0; tau < 2; tau++) {
        const f16* bp = Ut + (long)(g * 512 + s * 64 + 8 * w + tau * 4 + eo) * 512 + quad * 8;
#pragma unroll
        for (int ks = 0; ks < 16; ks++)
            bfr[tau][ks] = *(const half8*)(bp + ks * 32);
    }

    if (tid < 256) hbuf[0][tid] = 0u;   // h_{-1} = 0 (t=0 reads parity 0)
    float cst0 = 0.f, cst1 = 0.f;       // c-state of cols 8w+eo (tau0), 8w+4+eo (tau1)
    __syncthreads();                    // prologue full sync

    // xpre per-lane: gate g, cols (tau0, tau1) -> offsets +0, +4
    const f16* xb = xpre + (long)bb * T_ * NG + (g * 512 + s * 64 + 8 * w + eo);
    f16 xc0 = xb[0], xc1 = xb[4];       // t = 0

    for (int t = 0; t < T_; ++t) {
        // ---- acquire h_{t-1}: tid<256 polls one tagged slot (tight spin) ----
        if (t > 0 && tid < 256) {
            const u64* slot = hg64 + (size_t)(t & 1) * 8192 + bb * 256 + tid;
            const unsigned tag = (unsigned)t;
            u64 v;
            while ((unsigned)((v = __hip_atomic_load(slot, __ATOMIC_RELAXED,
                                                     __HIP_MEMORY_SCOPE_AGENT)) >> 32) != tag) {}
            hbuf[t & 1][tid] = (unsigned)v;
        }
        asm volatile("" ::: "memory");
        __builtin_amdgcn_sched_barrier(0);

        // ---- xpre prefetch for t+1 (consumed next iteration; nothing drains
        //      vmcnt before the NEXT poll -> full step of slack) ----
        f16 xn0 = (f16)0, xn1 = (f16)0;
        if (t < T_ - 1) {
            const f16* p = xb + (long)(t + 1) * NG;
            xn0 = p[0]; xn1 = p[4];
        }

        // ---- the ONE barrier: publish hbuf (LDS only; no vmcnt drain) ----
        asm volatile("s_waitcnt lgkmcnt(0)" ::: "memory");
        __builtin_amdgcn_s_barrier();
        __builtin_amdgcn_sched_barrier(0);

        // ---- h @ U via MFMA: A = h broadcast (conflict-free), shared by both tiles ----
        const unsigned* hb = hbuf[t & 1];
        float4v a00 = {0.f,0.f,0.f,0.f}, a01 = {0.f,0.f,0.f,0.f};   // tile0: ks even/odd
        float4v a10 = {0.f,0.f,0.f,0.f}, a11 = {0.f,0.f,0.f,0.f};   // tile1
#pragma unroll
        for (int ks = 0; ks < 16; ks += 2) {
            U4H8 av0, av1;
            av0.u = *(const uint4*)&hb[ks * 16 + quad * 4];
            av1.u = *(const uint4*)&hb[(ks + 1) * 16 + quad * 4];
            a00 = __builtin_amdgcn_mfma_f32_16x16x32_f16(av0.h, bfr[0][ks],     a00, 0, 0, 0);
            a10 = __builtin_amdgcn_mfma_f32_16x16x32_f16(av0.h, bfr[1][ks],     a10, 0, 0, 0);
            a01 = __builtin_amdgcn_mfma_f32_16x16x32_f16(av1.h, bfr[0][ks + 1], a01, 0, 0, 0);
            a11 = __builtin_amdgcn_mfma_f32_16x16x32_f16(av1.h, bfr[1][ks + 1], a11, 0, 0, 0);
        }
        // rows replicated -> reg0 of any lane = the dot for its col
        float pre0 = (a00[0] + a01[0]) + (float)xc0;
        float pre1 = (a10[0] + a11[0]) + (float)xc1;

        // ---- gates in-wave: lane computes ITS gate's activation, both taus ----
        const float mm = (g == 3) ? 2.f : -1.f;   // sigmoid: exp(-x); tanh: exp(2x)
        float e0 = __expf(mm * pre0), e1 = __expf(mm * pre1);
        float r0 = __builtin_amdgcn_rcpf(1.f + e0), r1 = __builtin_amdgcn_rcpf(1.f + e1);
        float act0 = (g == 3) ? 1.f - 2.f * r0 : r0;
        float act1 = (g == 3) ? 1.f - 2.f * r1 : r1;
        // butterfly gather across the gate index (lcol stride 4, 8)
        float p1_0 = __shfl_xor(act0, 4),  p2_0 = __shfl_xor(act0, 8),  p3_0 = __shfl_xor(p1_0, 8);
        float p1_1 = __shfl_xor(act1, 4),  p2_1 = __shfl_xor(act1, 8),  p3_1 = __shfl_xor(p1_1, 8);
        float gi0 = (g == 0) ? act0 : (g == 1) ? p1_0 : (g == 2) ? p2_0 : p3_0;
        float gf0 = (g == 1) ? act0 : (g == 0) ? p1_0 : (g == 3) ? p2_0 : p3_0;
        float gg0 = (g == 2) ? act0 : (g == 3) ? p1_0 : (g == 0) ? p2_0 : p3_0;
        float ct0 = (g == 3) ? act0 : (g == 2) ? p1_0 : (g == 1) ? p2_0 : p3_0;
        float gi1 = (g == 0) ? act1 : (g == 1) ? p1_1 : (g == 2) ? p2_1 : p3_1;
        float gf1 = (g == 1) ? act1 : (g == 0) ? p1_1 : (g == 3) ? p2_1 : p3_1;
        float gg1 = (g == 2) ? act1 : (g == 3) ? p1_1 : (g == 0) ? p2_1 : p3_1;
        float ct1 = (g == 3) ? act1 : (g == 2) ? p1_1 : (g == 1) ? p2_1 : p3_1;

        cst0 = gf0 * cst0 + gi0 * ct0;
        cst1 = gf1 * cst1 + gi1 * ct1;
        float h0 = gg0 * fast_tanh(cst0);    // col 8w+eo        (replicated x16 lanes)
        float h1 = gg1 * fast_tanh(cst1);    // col 8w+4+eo

        // ---- pack pairs + tagged release store (lanes 0 and 2 per wave) ----
        H16U c0v, c1v; c0v.h = (f16)h0; c1v.h = (f16)h1;
        unsigned hx0 = (unsigned)c0v.s, hx1 = (unsigned)c1v.s;
        unsigned hi0 = __shfl(hx0, lane + 1);   // partner col (odd eo)
        unsigned hi1 = __shfl(hx1, lane + 1);
        if (lane == 0 || lane == 2) {
            const int k = lane >> 1;            // 0 or 1
            unsigned pk0 = hx0 | (hi0 << 16);   // pair 4w+k   (tau0: cols 8w+2k, +1)
            unsigned pk1 = hx1 | (hi1 << 16);   // pair 4w+2+k (tau1: cols 8w+4+2k, +1)
            const size_t base = (size_t)((t + 1) & 1) * 8192 + (size_t)bb * 256 + s * 32 + 4 * w;
            const u64 tagw = (u64)(unsigned)(t + 1) << 32;
            __hip_atomic_store(hg64 + base + k,     tagw | (u64)pk0,
                               __ATOMIC_RELAXED, __HIP_MEMORY_SCOPE_AGENT);
            __hip_atomic_store(hg64 + base + 2 + k, tagw | (u64)pk1,
                               __ATOMIC_RELAXED, __HIP_MEMORY_SCOPE_AGENT);
            // history for gemm_hw (not on critical path)
            const long hbase = ((long)t * B_ + bb) * 256 + s * 32 + 4 * w;
            hs32[hbase + k]     = pk0;
            hs32[hbase + 2 + k] = pk1;
        }
        // rotate xpre pipeline registers
        xc0 = xn0; xc1 = xn1;
        // no trailing barrier: next poll writes the OTHER hbuf parity, and
        // slot-reuse is guarded by the tag protocol (see header comment)
    }
}

// ---------------- launch ----------------
extern "C" void kernel_launch(void* const* d_in, const int* in_sizes, int n_in,
                              void* d_out, int out_size, void* d_ws, size_t ws_size,
                              hipStream_t stream)
{
    const float* x  = (const float*)d_in[0];
    const float* Wi = (const float*)d_in[1];
    const float* Ui = (const float*)d_in[2];
    const float* Wf = (const float*)d_in[3];
    const float* Uf = (const float*)d_in[4];
    const float* Wg = (const float*)d_in[5];
    const float* Ug = (const float*)d_in[6];
    const float* Wc = (const float*)d_in[7];
    const float* Uc = (const float*)d_in[8];
    const float* Wo = (const float*)d_in[9];
    const float* bi = (const float*)d_in[10];
    const float* bf = (const float*)d_in[11];
    const float* bg = (const float*)d_in[12];
    const float* bc = (const float*)d_in[13];
    const float* bo = (const float*)d_in[14];

    char* ws = (char*)d_ws;
    f16*      x16   = (f16*)(ws + 0L);            // 64 MB
    f16*      xpre  = (f16*)(ws + 67108864L);     // 256 MB
    f16*      hs    = (f16*)(ws + 335544320L);    // 64 MB
    f16*      wt    = (f16*)(ws + 402653184L);    // 2 MB
    f16*      ut    = (f16*)(ws + 404750336L);    // 2 MB
    f16*      wot   = (f16*)(ws + 406847488L);    // 0.5 MB
    float*    bias  = (float*)(ws + 407371776L);  // 8 KB
    u64*      hg64  = (u64*)(ws + 407379968L);    // 128 KB tagged h exchange
    // hg64 is re-poisoned to 0xAA each call -> tag 0xAAAAAAAA never matches a
    // real t in [1,2048], so stale data cannot satisfy a poll.

    prep_cast<<<dim3(32768), dim3(256), 0, stream>>>(x, x16);
    prep_w<<<dim3(1024, 10), dim3(256), 0, stream>>>(Wi, Ui, Wf, Uf, Wg, Ug, Wc, Uc, Wo,
                                                     bi, bf, bg, bc, wt, ut, wot, bias);
    gemm_xw<<<dim3(16, 512), dim3(256), 0, stream>>>(x16, wt, bias, xpre);
    lstm_rec<<<dim3(256), dim3(512), 0, stream>>>(ut, xpre, hg64, (unsigned*)hs, 0);
    gemm_hw<<<dim3(4, 512), dim3(256), 0, stream>>>(hs, wot, bo, (float*)d_out);
}